// Round 2
// 427.416 us; speedup vs baseline: 1.0550x; 1.0550x over previous
//
#include <hip/hip_runtime.h>
#include <hip/hip_bf16.h>
#include <stdint.h>

#define T_DIM 16
#define B_DIM 4096
#define D_DIM 256
#define H_DIM 512
#define E_DIM 32
#define M_DIM (T_DIM * B_DIM)      // 65536 rows for the GEMMs
#define BD_DIM (B_DIM * D_DIM)     // 1048576 elems per t-slice
#define EPS_F 0.1f

typedef __attribute__((ext_vector_type(8))) short short8;   // 8 bf16 = 4 VGPRs (MFMA A/B frag)
typedef __attribute__((ext_vector_type(4))) float f32x4;    // MFMA C/D frag; also clang vec for nontemporal

#define GLOBAL_AS __attribute__((address_space(1)))
#define LDS_AS __attribute__((address_space(3)))

__device__ __forceinline__ uint32_t f2bf_rne(float x) {
  uint32_t u = __float_as_uint(x);
  return (u + 0x7fffu + ((u >> 16) & 1u)) >> 16;
}

__device__ __forceinline__ uint4 pack8(const float* f) {
  uint4 v;
  v.x = f2bf_rne(f[0]) | (f2bf_rne(f[1]) << 16);
  v.y = f2bf_rne(f[2]) | (f2bf_rne(f[3]) << 16);
  v.z = f2bf_rne(f[4]) | (f2bf_rne(f[5]) << 16);
  v.w = f2bf_rne(f[6]) | (f2bf_rne(f[7]) << 16);
  return v;
}

// ---- prep: convert f32 W1 (DxH) -> bf16 W1T (HxD); f32 W2 (HxD) -> bf16 W2T (DxH) ----
__global__ __launch_bounds__(256) void prep_kernel(
    const float* __restrict__ W1, const float* __restrict__ W2,
    uint16_t* __restrict__ W1T, uint16_t* __restrict__ W2T) {
  int idx = blockIdx.x * 256 + threadIdx.x;   // 0 .. 131071 (== D*H == H*D)
  if (idx < D_DIM * H_DIM) {
    int d = idx / H_DIM, h = idx % H_DIM;
    W1T[h * D_DIM + d] = (uint16_t)f2bf_rne(W1[idx]);   // W1T[h][d] = W1[d][h]
    int h2 = idx / D_DIM, d2 = idx % D_DIM;
    W2T[d2 * H_DIM + h2] = (uint16_t)f2bf_rne(W2[idx]); // W2T[d][h] = W2[h][d]
  }
}

// ---- agg = EPS*term + gathered edge messages (f32 in, f32 math, bf16 out) ----
// t-parallel: blockIdx.y = t (16x more blocks than the serial-t version -> full occupancy).
// pred/inv are streamed exactly once -> nontemporal loads keep term L3-resident for gathers.
__global__ __launch_bounds__(256) void agg_kernel(
    const float* __restrict__ term, const float* __restrict__ pred,
    const float* __restrict__ inv, const float* __restrict__ signs,
    const int* __restrict__ heads, const int* __restrict__ tails,
    uint16_t* __restrict__ agg) {
  __shared__ int sh_h[E_DIM], sh_t[E_DIM];
  __shared__ float sh_s[E_DIM];
  if (threadIdx.x < E_DIM) {
    int e = threadIdx.x;
    sh_h[e] = heads[e] & (T_DIM - 1);   // defensive clamp, values are 0..15
    sh_t[e] = tails[e] & (T_DIM - 1);
    sh_s[e] = signs[e];
  }
  __syncthreads();

  const int t = blockIdx.y;                            // one t-slice per block row
  const int j = (blockIdx.x * 256 + threadIdx.x) * 8;  // elem offset in [0, B*D)

  float acc[8];
  {
    f32x4 a = *reinterpret_cast<const f32x4*>(term + (size_t)t * BD_DIM + j);
    f32x4 b = *reinterpret_cast<const f32x4*>(term + (size_t)t * BD_DIM + j + 4);
    acc[0] = EPS_F * a[0]; acc[1] = EPS_F * a[1]; acc[2] = EPS_F * a[2]; acc[3] = EPS_F * a[3];
    acc[4] = EPS_F * b[0]; acc[5] = EPS_F * b[1]; acc[6] = EPS_F * b[2]; acc[7] = EPS_F * b[3];
  }

#pragma unroll 1
  for (int e = 0; e < E_DIM; ++e) {
    const float s = sh_s[e];
    if (sh_t[e] == t) {   // wave-uniform branch
      const f32x4* p = reinterpret_cast<const f32x4*>(pred + (size_t)e * BD_DIM + j);
      const float* hrow = term + (size_t)sh_h[e] * BD_DIM + j;
      f32x4 p0 = __builtin_nontemporal_load(p);
      f32x4 p1 = __builtin_nontemporal_load(p + 1);
      f32x4 h0 = *reinterpret_cast<const f32x4*>(hrow);
      f32x4 h1 = *reinterpret_cast<const f32x4*>(hrow + 4);
      acc[0] += s * (h0[0] + p0[0]); acc[1] += s * (h0[1] + p0[1]);
      acc[2] += s * (h0[2] + p0[2]); acc[3] += s * (h0[3] + p0[3]);
      acc[4] += s * (h1[0] + p1[0]); acc[5] += s * (h1[1] + p1[1]);
      acc[6] += s * (h1[2] + p1[2]); acc[7] += s * (h1[3] + p1[3]);
    }
    if (sh_h[e] == t) {   // wave-uniform branch
      const f32x4* iv = reinterpret_cast<const f32x4*>(inv + (size_t)e * BD_DIM + j);
      const float* trow = term + (size_t)sh_t[e] * BD_DIM + j;
      f32x4 i0 = __builtin_nontemporal_load(iv);
      f32x4 i1 = __builtin_nontemporal_load(iv + 1);
      f32x4 t0 = *reinterpret_cast<const f32x4*>(trow);
      f32x4 t1 = *reinterpret_cast<const f32x4*>(trow + 4);
      acc[0] += s * (t0[0] + i0[0]); acc[1] += s * (t0[1] + i0[1]);
      acc[2] += s * (t0[2] + i0[2]); acc[3] += s * (t0[3] + i0[3]);
      acc[4] += s * (t1[0] + i1[0]); acc[5] += s * (t1[1] + i1[1]);
      acc[6] += s * (t1[2] + i1[2]); acc[7] += s * (t1[3] + i1[3]);
    }
  }
  *reinterpret_cast<uint4*>(agg + (size_t)t * BD_DIM + j) = pack8(acc);
}

// ---- m97-style bf16 GEMM: C[M,N] = act(A[M,K] * Bt[N,K]^T + bias) ----
// block = 256 thr (4 waves); block tile 128x128; wave tile 64x64 (4x4 MFMA 16x16x32)
// A, Bt are bf16; bias is f32; output f32 or bf16 per OUT_F32.
template <int M, int N, int K, bool RELU, bool OUT_F32>
__global__ __launch_bounds__(256) void gemm_bt(
    const uint16_t* __restrict__ A, const uint16_t* __restrict__ Bt,
    const float* __restrict__ bias, void* __restrict__ Cout) {
  __shared__ __align__(16) uint16_t As[128 * 32];  // [row][k] 8 KB
  __shared__ __align__(16) uint16_t Bs[128 * 32];  // [n][k]   8 KB

  const int tid = threadIdx.x;
  const int w = tid >> 6;         // wave 0..3
  const int l = tid & 63;
  const int lane16 = l & 15;
  const int quad = l >> 4;
  const int wm = (w & 1) * 64;
  const int wn = (w >> 1) * 64;
  const int m0 = blockIdx.x * 128;
  const int n0 = blockIdx.y * 128;

  f32x4 acc[4][4];
#pragma unroll
  for (int i = 0; i < 4; ++i)
#pragma unroll
    for (int j = 0; j < 4; ++j) acc[i][j] = (f32x4){0.f, 0.f, 0.f, 0.f};

  const int srow = l >> 2;          // 16 rows per wave-call
  const int scol = (l & 3) * 8;     // 8 bf16 = 16 B per lane

  for (int k0 = 0; k0 < K; k0 += 32) {
    // stage A and Bt tiles: LDS dest = wave-uniform base + lane*16B (contract of global_load_lds)
#pragma unroll
    for (int c = 0; c < 2; ++c) {
      const int r = w * 32 + c * 16;
      const uint16_t* ga = A + (size_t)(m0 + r + srow) * K + k0 + scol;
      __builtin_amdgcn_global_load_lds((const GLOBAL_AS uint32_t*)ga,
                                       (LDS_AS uint32_t*)(As + r * 32), 16, 0, 0);
      const uint16_t* gb = Bt + (size_t)(n0 + r + srow) * K + k0 + scol;
      __builtin_amdgcn_global_load_lds((const GLOBAL_AS uint32_t*)gb,
                                       (LDS_AS uint32_t*)(Bs + r * 32), 16, 0, 0);
    }
    __syncthreads();

    short8 af[4], bfr[4];
#pragma unroll
    for (int i = 0; i < 4; ++i)
      af[i] = *reinterpret_cast<const short8*>(As + (wm + i * 16 + lane16) * 32 + quad * 8);
#pragma unroll
    for (int j = 0; j < 4; ++j)
      bfr[j] = *reinterpret_cast<const short8*>(Bs + (wn + j * 16 + lane16) * 32 + quad * 8);
#pragma unroll
    for (int i = 0; i < 4; ++i)
#pragma unroll
      for (int j = 0; j < 4; ++j)
        acc[i][j] = __builtin_amdgcn_mfma_f32_16x16x32_bf16(af[i], bfr[j], acc[i][j], 0, 0, 0);
    __syncthreads();
  }

  // epilogue: C/D layout col=lane&15, row=quad*4+reg (m89-verified)
#pragma unroll
  for (int j = 0; j < 4; ++j) {
    const int col = n0 + wn + j * 16 + lane16;
    const float bv = bias[col];
#pragma unroll
    for (int i = 0; i < 4; ++i) {
#pragma unroll
      for (int r = 0; r < 4; ++r) {
        const int row = m0 + wm + i * 16 + quad * 4 + r;
        float x = acc[i][j][r] + bv;
        if (RELU) x = fmaxf(x, 0.f);
        if (OUT_F32) {
          ((float*)Cout)[(size_t)row * N + col] = x;
        } else {
          ((uint16_t*)Cout)[(size_t)row * N + col] = (uint16_t)f2bf_rne(x);
        }
      }
    }
  }
}

extern "C" void kernel_launch(void* const* d_in, const int* in_sizes, int n_in,
                              void* d_out, int out_size, void* d_ws, size_t ws_size,
                              hipStream_t stream) {
  const float* term  = (const float*)d_in[0];
  const float* pred  = (const float*)d_in[1];
  const float* inv   = (const float*)d_in[2];
  const float* signs = (const float*)d_in[3];
  const float* W1    = (const float*)d_in[4];
  const float* b1    = (const float*)d_in[5];
  const float* W2    = (const float*)d_in[6];
  const float* b2    = (const float*)d_in[7];
  const int* heads   = (const int*)d_in[8];
  const int* tails   = (const int*)d_in[9];

  char* ws = (char*)d_ws;
  uint16_t* W1T    = (uint16_t*)(ws);                          // 512*256*2   = 256 KB
  uint16_t* W2T    = (uint16_t*)(ws + 262144);                 // 256*512*2   = 256 KB
  uint16_t* agg    = (uint16_t*)(ws + 524288);                 // 65536*256*2 = 32 MB
  uint16_t* hidden = (uint16_t*)(ws + 524288 + 33554432);      // 65536*512*2 = 64 MB

  prep_kernel<<<dim3(512), dim3(256), 0, stream>>>(W1, W2, W1T, W2T);
  agg_kernel<<<dim3(BD_DIM / 8 / 256, T_DIM), dim3(256), 0, stream>>>(
      term, pred, inv, signs, heads, tails, agg);
  gemm_bt<M_DIM, H_DIM, D_DIM, true, false><<<dim3(M_DIM / 128, H_DIM / 128), dim3(256), 0, stream>>>(
      agg, W1T, b1, (void*)hidden);
  gemm_bt<M_DIM, D_DIM, H_DIM, false, true><<<dim3(M_DIM / 128, D_DIM / 128), dim3(256), 0, stream>>>(
      hidden, W2T, b2, d_out);
}